// Round 8
// baseline (244.710 us; speedup 1.0000x reference)
//
#include <hip/hip_runtime.h>
#include <math.h>

#define EPS 1e-16f
#define SLOT 64
__device__ __forceinline__ float lrelu(float v) { return v > 0.0f ? v : 0.2f * v; }

// bf16 pack/unpack (RNE; inputs finite)
__device__ __forceinline__ unsigned short f2bf(float f) {
    unsigned u = __float_as_uint(f);
    u += 0x7FFF + ((u >> 16) & 1);
    return (unsigned short)(u >> 16);
}
__device__ __forceinline__ float bf2f(unsigned short s) {
    return __uint_as_float(((unsigned)s) << 16);
}

// ---------------- fused: single-pass slot-CSR scatter (blocks [0,D)) + layer-1 GEMM ----------
// Slot-CSR: node d's incoming-edge sources live at ssrc[d*64 .. d*64+deg[d]).
// deg ~ Poisson(16); P(deg>63) ~ 2e-18/node -> 64-slot never overflows (guarded anyway).
// Scatter: 8 edges/thread = 8 independent atomic chains. Scatter blocks FIRST; GEMM
// co-schedules behind atomic latency.
// GEMM: x[N,128] @ W1[128,64] -> h1 (bf16), + fused attention dots. BM=64,BN=64,K=128 whole;
// 4x4 micro-tile; pitches 129/65 (==1 mod 32) -> <=2-way conflicts.
#define LDK1 129
#define LDN1 65
__global__ __launch_bounds__(256, 2) void k_gemm1_scat(
    const float* __restrict__ x, const float* __restrict__ W1,
    const float* __restrict__ att_src1, const float* __restrict__ att_dst1,
    unsigned short* __restrict__ h1b, float* __restrict__ a_src1, float* __restrict__ a_dst1,
    int N, int D, const int* __restrict__ src, const int* __restrict__ dst,
    int* __restrict__ deg, int* __restrict__ ssrc, int E) {
    __shared__ float sX[64 * LDK1];    // [m][k]
    __shared__ float sW[128 * LDN1];   // [k][n]
    int t = threadIdx.x;
    if (blockIdx.x < D) {
        int e0 = (blockIdx.x * 256 + t) * 8;
        if (e0 < E) {
            int4 sa = *((const int4*)(src + e0));
            int4 sb = *((const int4*)(src + e0 + 4));
            int4 da = *((const int4*)(dst + e0));
            int4 db = *((const int4*)(dst + e0 + 4));
            int p0 = atomicAdd(&deg[da.x], 1);
            int p1 = atomicAdd(&deg[da.y], 1);
            int p2 = atomicAdd(&deg[da.z], 1);
            int p3 = atomicAdd(&deg[da.w], 1);
            int p4 = atomicAdd(&deg[db.x], 1);
            int p5 = atomicAdd(&deg[db.y], 1);
            int p6 = atomicAdd(&deg[db.z], 1);
            int p7 = atomicAdd(&deg[db.w], 1);
            if (p0 < SLOT) ssrc[(da.x << 6) + p0] = sa.x;
            if (p1 < SLOT) ssrc[(da.y << 6) + p1] = sa.y;
            if (p2 < SLOT) ssrc[(da.z << 6) + p2] = sa.z;
            if (p3 < SLOT) ssrc[(da.w << 6) + p3] = sa.w;
            if (p4 < SLOT) ssrc[(db.x << 6) + p4] = sb.x;
            if (p5 < SLOT) ssrc[(db.y << 6) + p5] = sb.y;
            if (p6 < SLOT) ssrc[(db.z << 6) + p6] = sb.z;
            if (p7 < SLOT) ssrc[(db.w << 6) + p7] = sb.w;
        }
        return;
    }
    int r0 = (blockIdx.x - D) * 64;
    // stage W1 (128x64)
    for (int i = t; i < 2048; i += 256) {        // i = k*16 + n4
        int k = i >> 4, n4 = i & 15;
        float4 v = ((const float4*)W1)[i];
        float* p = sW + k * LDN1 + 4 * n4;
        p[0] = v.x; p[1] = v.y; p[2] = v.z; p[3] = v.w;
    }
    // stage x rows r0..r0+63 (zero-pad tail)
    for (int i = t; i < 2048; i += 256) {        // i = m*32 + k4
        int m = i >> 5, k4 = i & 31;
        int r = r0 + m;
        float4 v = make_float4(0.f, 0.f, 0.f, 0.f);
        if (r < N) v = ((const float4*)(x + (size_t)r * 128))[k4];
        float* p = sX + m * LDK1 + 4 * k4;
        p[0] = v.x; p[1] = v.y; p[2] = v.z; p[3] = v.w;
    }
    __syncthreads();
    int tx = t & 15, ty = t >> 4;                // rows 4*tx.., cols 4*ty..
    const float* pA = sX + 4 * tx * LDK1;
    const float* pB = sW + 4 * ty;
    float c[4][4] = {{0.f}};
#pragma unroll 8
    for (int k = 0; k < 128; k++) {
        float a0 = pA[k], a1 = pA[LDK1 + k], a2 = pA[2 * LDK1 + k], a3 = pA[3 * LDK1 + k];
        const float* pb = pB + k * LDN1;
        float b0 = pb[0], b1 = pb[1], b2 = pb[2], b3 = pb[3];
        c[0][0] = fmaf(a0, b0, c[0][0]); c[0][1] = fmaf(a0, b1, c[0][1]);
        c[0][2] = fmaf(a0, b2, c[0][2]); c[0][3] = fmaf(a0, b3, c[0][3]);
        c[1][0] = fmaf(a1, b0, c[1][0]); c[1][1] = fmaf(a1, b1, c[1][1]);
        c[1][2] = fmaf(a1, b2, c[1][2]); c[1][3] = fmaf(a1, b3, c[1][3]);
        c[2][0] = fmaf(a2, b0, c[2][0]); c[2][1] = fmaf(a2, b1, c[2][1]);
        c[2][2] = fmaf(a2, b2, c[2][2]); c[2][3] = fmaf(a2, b3, c[2][3]);
        c[3][0] = fmaf(a3, b0, c[3][0]); c[3][1] = fmaf(a3, b1, c[3][1]);
        c[3][2] = fmaf(a3, b2, c[3][2]); c[3][3] = fmaf(a3, b3, c[3][3]);
    }
    // epilogue: write h1 as bf16, fused per-head attention dots (fp32 accumulators).
    float as0 = att_src1[4 * ty + 0], as1 = att_src1[4 * ty + 1],
          as2 = att_src1[4 * ty + 2], as3 = att_src1[4 * ty + 3];
    float ad0 = att_dst1[4 * ty + 0], ad1 = att_dst1[4 * ty + 1],
          ad2 = att_dst1[4 * ty + 2], ad3 = att_dst1[4 * ty + 3];
    __syncthreads();                              // done reading sX/sW; reuse sX as partials
    float* sPs = sX;                              // [row][17]
    float* sPd = sX + 64 * 17;
#pragma unroll
    for (int i = 0; i < 4; i++) {
        int row = 4 * tx + i;
        int r = r0 + row;
        if (r < N) {
            ushort4 hv;
            hv.x = f2bf(c[i][0]); hv.y = f2bf(c[i][1]);
            hv.z = f2bf(c[i][2]); hv.w = f2bf(c[i][3]);
            *((ushort4*)(h1b + (size_t)r * 64 + 4 * ty)) = hv;
        }
        sPs[row * 17 + ty] = fmaf(c[i][0], as0, fmaf(c[i][1], as1, fmaf(c[i][2], as2, c[i][3] * as3)));
        sPd[row * 17 + ty] = fmaf(c[i][0], ad0, fmaf(c[i][1], ad1, fmaf(c[i][2], ad2, c[i][3] * ad3)));
    }
    __syncthreads();
    for (int i = t; i < 512; i += 256) {          // i = row*8 + h
        int row = i >> 3, h = i & 7;
        int r = r0 + row;
        if (r < N) {
            a_src1[r * 8 + h] = sPs[row * 17 + 2 * h] + sPs[row * 17 + 2 * h + 1];
            a_dst1[r * 8 + h] = sPd[row * 17 + 2 * h] + sPd[row * 17 + 2 * h + 1];
        }
    }
}

// ---------------- layer 1: head-split per-dst softmax + aggregate (one wave/node/pass) -------
// Two passes over head-halves: pass p covers heads 4p..4p+3 = cols 32p..32p+31, i.e. the
// even/odd 64B lines of h1b. Per-pass gather working set = 3.2 MB < 4 MB XCD-L2 -> after
// warm-up every XCD's L2 holds the whole half; random gathers become local-L2 hits (was
// remote-L2/L3 at ~600cy, h1b=6.4MB thrashes a 4MB L2). Pass-0 blocks dispatch first so
// passes are temporally separated. Per pass:
//  phase A: ONE float4 gather per edge-lane = all 4 head logits (a_src1 rows are 32B).
//  phase B: uint loads (2 cols); 16 lanes/half-row -> 4 rows per instruction, each row
//           exactly one 64B line (perfect line efficiency). 2-deep pipelined.
// Lane l: colpair q=l&15 (cols 32p+2q,+1), row-group rg=l>>4; merge via shfl_xor(16,32).
__global__ __launch_bounds__(256) void k_node_agg1(
    const int* __restrict__ deg, const int* __restrict__ ssrc,
    const float* __restrict__ a_src1, const float* __restrict__ a_dst1,
    const unsigned short* __restrict__ h1b, const float* __restrict__ bias1,
    float* __restrict__ xx, int N, int NB) {
    int pass = (blockIdx.x >= NB) ? 1 : 0;
    int nb = blockIdx.x - pass * NB;
    int d = (nb * 256 + threadIdx.x) >> 6;
    int lane = threadIdx.x & 63;
    if (d >= N) return;
    int start = d << 6;
    int m = min(deg[d], SLOT);                    // wave-uniform
    // coalesced slot-row load: lane i holds src of edge i (0 for i>=m -> safe row-0)
    int s_lane = 0;
    if (lane < m) s_lane = ssrc[start + lane];
    // phase A: 4-head logits for edge `lane` (one float4 gather)
    float4 ad4 = *((const float4*)(a_dst1 + (size_t)d * 8 + 4 * pass));
    float4 as4 = *((const float4*)(a_src1 + (size_t)s_lane * 8 + 4 * pass));
    float e0 = 0.f, e1 = 0.f, e2 = 0.f, e3 = 0.f;
    if (lane < m) {
        e0 = __expf(lrelu(as4.x + ad4.x));
        e1 = __expf(lrelu(as4.y + ad4.y));
        e2 = __expf(lrelu(as4.z + ad4.z));
        e3 = __expf(lrelu(as4.w + ad4.w));
    }
    // denominators per head (full-wave butterfly)
    float t0 = e0, t1 = e1, t2 = e2, t3 = e3;
#pragma unroll
    for (int off = 32; off; off >>= 1) {
        t0 += __shfl_xor(t0, off); t1 += __shfl_xor(t1, off);
        t2 += __shfl_xor(t2, off); t3 += __shfl_xor(t3, off);
    }
    int q = lane & 15;                            // colpair: cols 32p+2q, +1
    int rg = lane >> 4;                           // row-group 0..3
    int hsel = q >> 2;                            // head component owning this colpair
    int coff = 32 * pass + 2 * q;                 // element offset in h1b row
    int nblk = (m + 3) >> 2;                      // 4-edge groups
    float accLo = 0.f, accHi = 0.f;
    // prime group 0 (edges rg)
    unsigned rA = 0; float fA = 0.f;
    {
        int sR = __shfl(s_lane, rg);
        rA = *((const unsigned*)(h1b + (size_t)sR * 64 + coff));
        float c0 = __shfl(e0, rg), c1 = __shfl(e1, rg), c2 = __shfl(e2, rg), c3 = __shfl(e3, rg);
        fA = hsel == 0 ? c0 : hsel == 1 ? c1 : hsel == 2 ? c2 : c3;
    }
#pragma unroll
    for (int jb = 0; jb < 16; jb++) {
        if (jb >= nblk) break;                    // wave-uniform
        unsigned rB = 0; float fB = 0.f;
        if (jb + 1 < nblk) {
            int eidx = (jb + 1) * 4 + rg;
            int sR = __shfl(s_lane, eidx);
            rB = *((const unsigned*)(h1b + (size_t)sR * 64 + coff));
            float c0 = __shfl(e0, eidx), c1 = __shfl(e1, eidx);
            float c2 = __shfl(e2, eidx), c3 = __shfl(e3, eidx);
            fB = hsel == 0 ? c0 : hsel == 1 ? c1 : hsel == 2 ? c2 : c3;
        }
        accLo = fmaf(fA, bf2f((unsigned short)(rA & 0xffff)), accLo);
        accHi = fmaf(fA, bf2f((unsigned short)(rA >> 16)), accHi);
        rA = rB; fA = fB;
    }
    // merge 4 row-groups (lanes l, l^16, l^32, l^48 share a colpair)
    accLo += __shfl_xor(accLo, 16); accHi += __shfl_xor(accHi, 16);
    accLo += __shfl_xor(accLo, 32); accHi += __shfl_xor(accHi, 32);
    float lsum = hsel == 0 ? t0 : hsel == 1 ? t1 : hsel == 2 ? t2 : t3;
    if (lane < 16) {
        float2 bz = ((const float2*)(bias1 + 32 * pass))[q];
        float oLo = accLo / (lsum + EPS) + bz.x;
        float oHi = accHi / (lsum + EPS) + bz.y;
        oLo = oLo > 0.0f ? oLo : expm1f(oLo);     // ELU
        oHi = oHi > 0.0f ? oHi : expm1f(oHi);
        *((float2*)(xx + (size_t)d * 64 + 32 * pass + 2 * q)) = make_float2(oLo, oHi);
    }
}

// ---------------- layer 2 GEMM: xx[N,64] @ W2[64,40] -> h2, + fused attention dots ----
#define LDK2 65
#define LDN2 41
__global__ __launch_bounds__(256, 2) void k_gemm2(
    const float* __restrict__ xx, const float* __restrict__ W2,
    const float* __restrict__ att_src2, const float* __restrict__ att_dst2,
    float* __restrict__ h2, float* __restrict__ a_src2, float* __restrict__ a_dst2, int N) {
    __shared__ float sX[64 * LDK2];    // [m][k]
    __shared__ float sW[64 * LDN2];    // [k][n]
    int t = threadIdx.x;
    int r0 = blockIdx.x * 64;
    for (int i = t; i < 640; i += 256) {          // i = k*10 + n4
        int k = i / 10, n4 = i - k * 10;
        float4 v = ((const float4*)W2)[i];
        float* p = sW + k * LDN2 + 4 * n4;
        p[0] = v.x; p[1] = v.y; p[2] = v.z; p[3] = v.w;
    }
    for (int i = t; i < 1024; i += 256) {         // i = m*16 + k4
        int m = i >> 4, k4 = i & 15;
        int r = r0 + m;
        float4 v = make_float4(0.f, 0.f, 0.f, 0.f);
        if (r < N) v = ((const float4*)(xx + (size_t)r * 64))[k4];
        float* p = sX + m * LDK2 + 4 * k4;
        p[0] = v.x; p[1] = v.y; p[2] = v.z; p[3] = v.w;
    }
    __syncthreads();
    int tx = t & 15, ty = t >> 4;
    bool act = ty < 10;
    float c[4][4] = {{0.f}};
    if (act) {
        const float* pA = sX + 4 * tx * LDK2;
        const float* pB = sW + 4 * ty;
#pragma unroll 8
        for (int k = 0; k < 64; k++) {
            float a0 = pA[k], a1 = pA[LDK2 + k], a2 = pA[2 * LDK2 + k], a3 = pA[3 * LDK2 + k];
            const float* pb = pB + k * LDN2;
            float b0 = pb[0], b1 = pb[1], b2 = pb[2], b3 = pb[3];
            c[0][0] = fmaf(a0, b0, c[0][0]); c[0][1] = fmaf(a0, b1, c[0][1]);
            c[0][2] = fmaf(a0, b2, c[0][2]); c[0][3] = fmaf(a0, b3, c[0][3]);
            c[1][0] = fmaf(a1, b0, c[1][0]); c[1][1] = fmaf(a1, b1, c[1][1]);
            c[1][2] = fmaf(a1, b2, c[1][2]); c[1][3] = fmaf(a1, b3, c[1][3]);
            c[2][0] = fmaf(a2, b0, c[2][0]); c[2][1] = fmaf(a2, b1, c[2][1]);
            c[2][2] = fmaf(a2, b2, c[2][2]); c[2][3] = fmaf(a2, b3, c[2][3]);
            c[3][0] = fmaf(a3, b0, c[3][0]); c[3][1] = fmaf(a3, b1, c[3][1]);
            c[3][2] = fmaf(a3, b2, c[3][2]); c[3][3] = fmaf(a3, b3, c[3][3]);
        }
    }
    float as0 = 0.f, as1 = 0.f, as2 = 0.f, as3 = 0.f;
    float ad0 = 0.f, ad1 = 0.f, ad2 = 0.f, ad3 = 0.f;
    if (act) {
        as0 = att_src2[4 * ty + 0]; as1 = att_src2[4 * ty + 1];
        as2 = att_src2[4 * ty + 2]; as3 = att_src2[4 * ty + 3];
        ad0 = att_dst2[4 * ty + 0]; ad1 = att_dst2[4 * ty + 1];
        ad2 = att_dst2[4 * ty + 2]; ad3 = att_dst2[4 * ty + 3];
    }
    __syncthreads();                              // reuse sX as partials [row][11]
    float* sPs = sX;
    float* sPd = sX + 64 * 11;
#pragma unroll
    for (int i = 0; i < 4; i++) {
        int row = 4 * tx + i;
        int r = r0 + row;
        if (act) {
            if (r < N) {
                float4 hv = make_float4(c[i][0], c[i][1], c[i][2], c[i][3]);
                *((float4*)(h2 + (size_t)r * 40 + 4 * ty)) = hv;
            }
            sPs[row * 11 + ty] = fmaf(c[i][0], as0, fmaf(c[i][1], as1, fmaf(c[i][2], as2, c[i][3] * as3)));
            sPd[row * 11 + ty] = fmaf(c[i][0], ad0, fmaf(c[i][1], ad1, fmaf(c[i][2], ad2, c[i][3] * ad3)));
        }
    }
    __syncthreads();
    if (t < 64) {
        int r = r0 + t;
        if (r < N) {
            float ps = 0.f, pd = 0.f;
#pragma unroll
            for (int j = 0; j < 10; j++) {
                ps += sPs[t * 11 + j];
                pd += sPd[t * 11 + j];
            }
            a_src2[r] = ps;
            a_dst2[r] = pd;
        }
    }
}

// ---------------- layer 2: per-dst-node softmax + aggregate ----------------
// Triple-row gathers: each lane loads a float2 (2 cols of a 40-col h2 row); 20 lanes/row ->
// one instruction covers THREE rows (lanes 60-63 idle). Gather instruction count -> m/3.
// Lane accumulates col pair (2*q20, 2*q20+1) over edges j==grp (mod 3); groups merged with
// two indexed shuffles. Invalid j -> f=0 with safe row (clamped shuffle index).
__global__ __launch_bounds__(256) void k_node_agg2(
    const int* __restrict__ deg, const int* __restrict__ ssrc,
    const float* __restrict__ a_src2, const float* __restrict__ a_dst2,
    const float* __restrict__ h2, const float* __restrict__ bias2,
    float* __restrict__ out, int N) {
    int d = (blockIdx.x * 256 + threadIdx.x) >> 6;
    int lane = threadIdx.x & 63;
    if (d >= N) return;
    int start = d << 6;
    int m = min(deg[d], SLOT);                    // wave-uniform
    float adst = a_dst2[d];
    // coalesced slot-row load; per-lane logit (0 for lane>=m)
    int s_l = 0; float ex_l = 0.0f;
    if (lane < m) {
        s_l = ssrc[start + lane];
        ex_l = __expf(lrelu(a_src2[s_l] + adst));
    }
    int grp = lane / 20;                          // 0,1,2 gather groups; 3 = idle lanes
    int q20 = lane - grp * 20;                    // col-pair index within row
    bool gact = grp < 3;
    int nin = (m + 2) / 3;                        // gather instructions
    int nblk = (nin + 3) >> 2;                    // blocks of 4 instructions (<=6)
    float aLo = 0.0f, aHi = 0.0f;
    auto loadb = [&](int b, float2* g, float* f) {
#pragma unroll
        for (int k2 = 0; k2 < 4; k2++) {
            int j = 3 * (4 * b + k2) + grp;       // edge index
            int jm = j & 63;                      // clamp for shuffle validity
            int sR = __shfl(s_l, jm);
            float fv = __shfl(ex_l, jm);
            f[k2] = (gact && j < m) ? fv : 0.0f;
            g[k2] = *((const float2*)(h2 + (size_t)sR * 40 + 2 * q20));
        }
    };
    float2 gA[4]; float fA[4];
    if (nblk > 0) loadb(0, gA, fA);
#pragma unroll
    for (int b = 0; b < 6; b++) {
        if (b >= nblk) break;                     // wave-uniform
        float2 gB[4]; float fB[4];
        if (b + 1 < nblk) loadb(b + 1, gB, fB);
#pragma unroll
        for (int k2 = 0; k2 < 4; k2++) {
            aLo = fmaf(fA[k2], gA[k2].x, aLo);
            aHi = fmaf(fA[k2], gA[k2].y, aHi);
        }
        if (b + 1 < nblk) {
#pragma unroll
            for (int k2 = 0; k2 < 4; k2++) { gA[k2] = gB[k2]; fA[k2] = fB[k2]; }
        }
    }
    // merge the 3 edge groups (lanes l, l+20, l+40 hold the same col pair)
    int i1 = (lane + 20) & 63, i2 = (lane + 40) & 63;
    float ml1 = __shfl(aLo, i1), ml2 = __shfl(aLo, i2);
    float mh1 = __shfl(aHi, i1), mh2 = __shfl(aHi, i2);
    aLo += ml1 + ml2;
    aHi += mh1 + mh2;
    // denominator: full-wave reduce of per-lane logits
    float t = ex_l;
#pragma unroll
    for (int off = 32; off; off >>= 1) t += __shfl_xor(t, off);
    if (lane < 20) {
        float2 bz = ((const float2*)bias2)[lane];
        float oLo = aLo / (t + EPS) + bz.x;
        float oHi = aHi / (t + EPS) + bz.y;
        *((float2*)(out + (size_t)d * 40 + 2 * lane)) = make_float2(oLo, oHi);
    }
}

// ---------------- launch ----------------
extern "C" void kernel_launch(void* const* d_in, const int* in_sizes, int n_in,
                              void* d_out, int out_size, void* d_ws, size_t ws_size,
                              hipStream_t stream) {
    const float* x        = (const float*)d_in[0];
    const int*   ei       = (const int*)d_in[1];
    const float* W1       = (const float*)d_in[2];
    const float* att_src1 = (const float*)d_in[3];
    const float* att_dst1 = (const float*)d_in[4];
    const float* bias1    = (const float*)d_in[5];
    const float* W2       = (const float*)d_in[6];
    const float* att_src2 = (const float*)d_in[7];
    const float* att_dst2 = (const float*)d_in[8];
    const float* bias2    = (const float*)d_in[9];
    float* out = (float*)d_out;

    const int N = in_sizes[0] / 128;   // 50000
    const int E = in_sizes[1] / 2;     // 800000
    const int* src = ei;
    const int* dst = ei + E;

    // workspace layout (slot-CSR: no rowptr/cursor/blocksum; ssrc is N*64 slots)
    float* ws = (float*)d_ws;
    size_t off = 0;
    int*   deg      = (int*)(ws + off); off += (size_t)N;
    int*   ssrc     = (int*)(ws + off); off += (size_t)N * SLOT;
    unsigned short* h1b = (unsigned short*)(ws + off); off += (size_t)N * 32;  // bf16 N*64
    float* a_src1   = ws + off; off += (size_t)N * 8;
    float* a_dst1   = ws + off; off += (size_t)N * 8;
    float* xx       = ws + off; off += (size_t)N * 64;
    float* h2       = ws + off; off += (size_t)N * 40;
    float* a_src2   = ws + off; off += (size_t)N;
    float* a_dst2   = ws + off; off += (size_t)N;

    const int B = 256;
    int G1 = (N + 63) / 64;               // gemm blocks (782)
    int D  = (E / 8 + 255) / 256;         // scatter blocks (8 edges/thread, 391)
    int NB = (N + 3) / 4;                 // node blocks per pass (12500)

    hipMemsetAsync(deg, 0, (size_t)N * sizeof(int), stream);
    // single-pass slot-CSR scatter fused with gemm1 (+ attention dots): scatter blocks
    // first (critical path), GEMM co-schedules behind atomic latency
    k_gemm1_scat<<<D + G1, B, 0, stream>>>(x, W1, att_src1, att_dst1, h1b, a_src1, a_dst1,
                                           N, D, src, dst, deg, ssrc, E);
    // head-split: pass 0 (heads 0-3) blocks dispatch first, then pass 1 (heads 4-7)
    k_node_agg1<<<2 * NB, B, 0, stream>>>(deg, ssrc, a_src1, a_dst1, h1b, bias1, xx, N, NB);
    k_gemm2<<<G1, B, 0, stream>>>(xx, W2, att_src2, att_dst2, h2, a_src2, a_dst2, N);
    k_node_agg2<<<(N + 3) / 4, B, 0, stream>>>(deg, ssrc, a_src2, a_dst2, h2, bias2, out, N);
}

// Round 9
// 216.331 us; speedup vs baseline: 1.1312x; 1.1312x over previous
//
#include <hip/hip_runtime.h>
#include <math.h>

#define EPS 1e-16f
#define SLOT 64
__device__ __forceinline__ float lrelu(float v) { return v > 0.0f ? v : 0.2f * v; }

// bf16 pack/unpack (RNE; inputs finite)
__device__ __forceinline__ unsigned short f2bf(float f) {
    unsigned u = __float_as_uint(f);
    u += 0x7FFF + ((u >> 16) & 1);
    return (unsigned short)(u >> 16);
}
__device__ __forceinline__ float bf2f(unsigned short s) {
    return __uint_as_float(((unsigned)s) << 16);
}

// ---------------- fused: single-pass slot-CSR scatter (blocks [0,D)) + layer-1 GEMM ----------
// Slot-CSR: node d's incoming-edge sources live at ssrc[d*64 .. d*64+deg[d]).
// deg ~ Poisson(16); P(deg>63) ~ 2e-18/node -> 64-slot never overflows (guarded anyway).
// Scatter: 8 edges/thread = 8 independent atomic chains. Scatter blocks FIRST; GEMM
// co-schedules behind atomic latency.
// OCCUPANCY FIX: GEMM LDS halved via K-split double-pass (sX/sW are K=64 halves, 33.3KB
// total vs 66.5KB). Scatter blocks reserve the kernel's LDS too -> 2 blocks/CU was choking
// the latency-bound scatter at 8 waves/CU; now 4 blocks/CU = 16 waves/CU.
// GEMM: x[N,128] @ W1[128,64] -> h1 (bf16), + fused attention dots. BM=64,BN=64, K in two
// 64-halves; 4x4 micro-tile; pitch 65 (==1 mod 32) -> <=2-way conflicts.
#define LDP 65
__global__ __launch_bounds__(256, 4) void k_gemm1_scat(
    const float* __restrict__ x, const float* __restrict__ W1,
    const float* __restrict__ att_src1, const float* __restrict__ att_dst1,
    unsigned short* __restrict__ h1b, float* __restrict__ a_src1, float* __restrict__ a_dst1,
    int N, int D, const int* __restrict__ src, const int* __restrict__ dst,
    int* __restrict__ deg, int* __restrict__ ssrc, int E) {
    __shared__ float sX[64 * LDP];     // [m][k-half]  16.6KB
    __shared__ float sW[64 * LDP];     // [k-half][n]  16.6KB
    int t = threadIdx.x;
    if (blockIdx.x < D) {
        int e0 = (blockIdx.x * 256 + t) * 8;
        if (e0 < E) {
            int4 sa = *((const int4*)(src + e0));
            int4 sb = *((const int4*)(src + e0 + 4));
            int4 da = *((const int4*)(dst + e0));
            int4 db = *((const int4*)(dst + e0 + 4));
            int p0 = atomicAdd(&deg[da.x], 1);
            int p1 = atomicAdd(&deg[da.y], 1);
            int p2 = atomicAdd(&deg[da.z], 1);
            int p3 = atomicAdd(&deg[da.w], 1);
            int p4 = atomicAdd(&deg[db.x], 1);
            int p5 = atomicAdd(&deg[db.y], 1);
            int p6 = atomicAdd(&deg[db.z], 1);
            int p7 = atomicAdd(&deg[db.w], 1);
            if (p0 < SLOT) ssrc[(da.x << 6) + p0] = sa.x;
            if (p1 < SLOT) ssrc[(da.y << 6) + p1] = sa.y;
            if (p2 < SLOT) ssrc[(da.z << 6) + p2] = sa.z;
            if (p3 < SLOT) ssrc[(da.w << 6) + p3] = sa.w;
            if (p4 < SLOT) ssrc[(db.x << 6) + p4] = sb.x;
            if (p5 < SLOT) ssrc[(db.y << 6) + p5] = sb.y;
            if (p6 < SLOT) ssrc[(db.z << 6) + p6] = sb.z;
            if (p7 < SLOT) ssrc[(db.w << 6) + p7] = sb.w;
        }
        return;
    }
    int r0 = (blockIdx.x - D) * 64;
    int tx = t & 15, ty = t >> 4;                // rows 4*tx.., cols 4*ty..
    float c[4][4] = {{0.f}};
#pragma unroll
    for (int kh = 0; kh < 2; kh++) {
        // stage W1 half: rows 64*kh..+63 (64x64)
        for (int i = t; i < 1024; i += 256) {    // i = k*16 + n4
            int k = i >> 4, n4 = i & 15;
            float4 v = ((const float4*)W1)[(64 * kh + k) * 16 + n4];
            float* p = sW + k * LDP + 4 * n4;
            p[0] = v.x; p[1] = v.y; p[2] = v.z; p[3] = v.w;
        }
        // stage x half: rows r0..r0+63, cols 64*kh..+63 (zero-pad row tail)
        for (int i = t; i < 1024; i += 256) {    // i = m*16 + k4
            int m = i >> 4, k4 = i & 15;
            int r = r0 + m;
            float4 v = make_float4(0.f, 0.f, 0.f, 0.f);
            if (r < N) v = ((const float4*)(x + (size_t)r * 128))[16 * kh + k4];
            float* p = sX + m * LDP + 4 * k4;
            p[0] = v.x; p[1] = v.y; p[2] = v.z; p[3] = v.w;
        }
        __syncthreads();
        const float* pA = sX + 4 * tx * LDP;
        const float* pB = sW + 4 * ty;
#pragma unroll 8
        for (int k = 0; k < 64; k++) {
            float a0 = pA[k], a1 = pA[LDP + k], a2 = pA[2 * LDP + k], a3 = pA[3 * LDP + k];
            const float* pb = pB + k * LDP;
            float b0 = pb[0], b1 = pb[1], b2 = pb[2], b3 = pb[3];
            c[0][0] = fmaf(a0, b0, c[0][0]); c[0][1] = fmaf(a0, b1, c[0][1]);
            c[0][2] = fmaf(a0, b2, c[0][2]); c[0][3] = fmaf(a0, b3, c[0][3]);
            c[1][0] = fmaf(a1, b0, c[1][0]); c[1][1] = fmaf(a1, b1, c[1][1]);
            c[1][2] = fmaf(a1, b2, c[1][2]); c[1][3] = fmaf(a1, b3, c[1][3]);
            c[2][0] = fmaf(a2, b0, c[2][0]); c[2][1] = fmaf(a2, b1, c[2][1]);
            c[2][2] = fmaf(a2, b2, c[2][2]); c[2][3] = fmaf(a2, b3, c[2][3]);
            c[3][0] = fmaf(a3, b0, c[3][0]); c[3][1] = fmaf(a3, b1, c[3][1]);
            c[3][2] = fmaf(a3, b2, c[3][2]); c[3][3] = fmaf(a3, b3, c[3][3]);
        }
        __syncthreads();                          // before restaging / epilogue reuse
    }
    // epilogue: write h1 as bf16, fused per-head attention dots (fp32 accumulators).
    float as0 = att_src1[4 * ty + 0], as1 = att_src1[4 * ty + 1],
          as2 = att_src1[4 * ty + 2], as3 = att_src1[4 * ty + 3];
    float ad0 = att_dst1[4 * ty + 0], ad1 = att_dst1[4 * ty + 1],
          ad2 = att_dst1[4 * ty + 2], ad3 = att_dst1[4 * ty + 3];
    float* sPs = sX;                              // [row][17]
    float* sPd = sX + 64 * 17;
#pragma unroll
    for (int i = 0; i < 4; i++) {
        int row = 4 * tx + i;
        int r = r0 + row;
        if (r < N) {
            ushort4 hv;
            hv.x = f2bf(c[i][0]); hv.y = f2bf(c[i][1]);
            hv.z = f2bf(c[i][2]); hv.w = f2bf(c[i][3]);
            *((ushort4*)(h1b + (size_t)r * 64 + 4 * ty)) = hv;
        }
        sPs[row * 17 + ty] = fmaf(c[i][0], as0, fmaf(c[i][1], as1, fmaf(c[i][2], as2, c[i][3] * as3)));
        sPd[row * 17 + ty] = fmaf(c[i][0], ad0, fmaf(c[i][1], ad1, fmaf(c[i][2], ad2, c[i][3] * ad3)));
    }
    __syncthreads();
    for (int i = t; i < 512; i += 256) {          // i = row*8 + h
        int row = i >> 3, h = i & 7;
        int r = r0 + row;
        if (r < N) {
            a_src1[r * 8 + h] = sPs[row * 17 + 2 * h] + sPs[row * 17 + 2 * h + 1];
            a_dst1[r * 8 + h] = sPd[row * 17 + 2 * h] + sPd[row * 17 + 2 * h + 1];
        }
    }
}

// ---------------- layer 1: per-dst-node softmax + aggregate (one wave per node) ----------------
// (round-7 dual-row form — best measured; head-split regressed and was reverted)
// Dual-row gathers: each lane loads a uint (2 bf16 cols); lanes 0-31 cover row A, lanes
// 32-63 cover row B -> ONE instruction gathers TWO h1b rows. Lane l accumulates col pair
// (2q,2q+1), q=l&31, over its edge-parity half (sub=l>>5); merged with shfl_xor(32).
__global__ __launch_bounds__(256) void k_node_agg1(
    const int* __restrict__ deg, const int* __restrict__ ssrc,
    const float* __restrict__ a_src1, const float* __restrict__ a_dst1,
    const unsigned short* __restrict__ h1b, const float* __restrict__ bias1,
    float* __restrict__ xx, int N) {
    int d = (blockIdx.x * 256 + threadIdx.x) >> 6;
    int lane = threadIdx.x & 63;
    if (d >= N) return;
    int start = d << 6;
    int m = min(deg[d], SLOT);                    // wave-uniform
    int h8 = lane & 7;      // head this lane covers in phase A
    int eoff = lane >> 3;   // edge-in-chunk this lane covers in phase A
    int q = lane & 31;      // col-pair index: cols 2q, 2q+1
    int hsel = q >> 2;      // head owning the col pair
    int sub = lane >> 5;    // 0: even edges-in-pair, 1: odd
    float adst8 = a_dst1[d * 8 + h8];
    // coalesced slot-row load: lane i holds src of edge i (0 for i>=m -> safe row-0)
    int s_lane = 0;
    if (lane < m) s_lane = ssrc[start + lane];
    int nch = (m + 7) >> 3;                       // 8-edge chunks
    // prime chunk-0 gathers (4 dual-row uint loads), fly under phase A
    unsigned rA[4];
#pragma unroll
    for (int k = 0; k < 4; k++) {
        int sR = __shfl(s_lane, 2 * k + sub);
        rA[k] = *((const unsigned*)(h1b + (size_t)sR * 64 + (q << 1)));
    }
    // phase A: per-edge logits, 8 edges x 8 heads in parallel
    float exv[8];
    float lsumA = 0.0f;
#pragma unroll
    for (int c = 0; c < 8; c++) {
        int idx = c * 8 + eoff;
        int s_c = __shfl(s_lane, idx);
        float e = 0.0f;
        if (idx < m) e = __expf(lrelu(a_src1[(size_t)s_c * 8 + h8] + adst8));
        exv[c] = e;
        lsumA += e;
    }
    // phase B: 2-deep pipelined chunks, 4 dual-row gathers per chunk
    float accLo = 0.0f, accHi = 0.0f;
#pragma unroll
    for (int c = 0; c < 8; c++) {
        if (c >= nch) break;                      // wave-uniform
        unsigned rB[4];
        if (c + 1 < nch) {
#pragma unroll
            for (int k = 0; k < 4; k++) {
                int sR = __shfl(s_lane, (c + 1) * 8 + 2 * k + sub);
                rB[k] = *((const unsigned*)(h1b + (size_t)sR * 64 + (q << 1)));
            }
        }
#pragma unroll
        for (int k = 0; k < 4; k++) {
            float f = __shfl(exv[c], ((2 * k + sub) << 3) | hsel);
            accLo = fmaf(f, bf2f((unsigned short)(rA[k] & 0xffff)), accLo);
            accHi = fmaf(f, bf2f((unsigned short)(rA[k] >> 16)), accHi);
        }
        if (c + 1 < nch) {
#pragma unroll
            for (int k = 0; k < 4; k++) rA[k] = rB[k];
        }
    }
    // merge even/odd edge halves (lane l <-> l+32 hold same col pair)
    accLo += __shfl_xor(accLo, 32);
    accHi += __shfl_xor(accHi, 32);
    // denom: reduce lsumA over edge-offset bits (3..5) -> per-head sums; broadcast
    float t = lsumA;
    t += __shfl_xor(t, 8); t += __shfl_xor(t, 16); t += __shfl_xor(t, 32);
    float lsum = __shfl(t, hsel);
    if (lane < 32) {
        float2 bz = ((const float2*)bias1)[q];
        float oLo = accLo / (lsum + EPS) + bz.x;
        float oHi = accHi / (lsum + EPS) + bz.y;
        oLo = oLo > 0.0f ? oLo : expm1f(oLo);     // ELU
        oHi = oHi > 0.0f ? oHi : expm1f(oHi);
        *((float2*)(xx + (size_t)d * 64 + 2 * q)) = make_float2(oLo, oHi);
    }
}

// ---------------- layer 2 GEMM: xx[N,64] @ W2[64,40] -> h2, + fused attention dots ----
#define LDK2 65
#define LDN2 41
__global__ __launch_bounds__(256, 2) void k_gemm2(
    const float* __restrict__ xx, const float* __restrict__ W2,
    const float* __restrict__ att_src2, const float* __restrict__ att_dst2,
    float* __restrict__ h2, float* __restrict__ a_src2, float* __restrict__ a_dst2, int N) {
    __shared__ float sX[64 * LDK2];    // [m][k]
    __shared__ float sW[64 * LDN2];    // [k][n]
    int t = threadIdx.x;
    int r0 = blockIdx.x * 64;
    for (int i = t; i < 640; i += 256) {          // i = k*10 + n4
        int k = i / 10, n4 = i - k * 10;
        float4 v = ((const float4*)W2)[i];
        float* p = sW + k * LDN2 + 4 * n4;
        p[0] = v.x; p[1] = v.y; p[2] = v.z; p[3] = v.w;
    }
    for (int i = t; i < 1024; i += 256) {         // i = m*16 + k4
        int m = i >> 4, k4 = i & 15;
        int r = r0 + m;
        float4 v = make_float4(0.f, 0.f, 0.f, 0.f);
        if (r < N) v = ((const float4*)(xx + (size_t)r * 64))[k4];
        float* p = sX + m * LDK2 + 4 * k4;
        p[0] = v.x; p[1] = v.y; p[2] = v.z; p[3] = v.w;
    }
    __syncthreads();
    int tx = t & 15, ty = t >> 4;
    bool act = ty < 10;
    float c[4][4] = {{0.f}};
    if (act) {
        const float* pA = sX + 4 * tx * LDK2;
        const float* pB = sW + 4 * ty;
#pragma unroll 8
        for (int k = 0; k < 64; k++) {
            float a0 = pA[k], a1 = pA[LDK2 + k], a2 = pA[2 * LDK2 + k], a3 = pA[3 * LDK2 + k];
            const float* pb = pB + k * LDN2;
            float b0 = pb[0], b1 = pb[1], b2 = pb[2], b3 = pb[3];
            c[0][0] = fmaf(a0, b0, c[0][0]); c[0][1] = fmaf(a0, b1, c[0][1]);
            c[0][2] = fmaf(a0, b2, c[0][2]); c[0][3] = fmaf(a0, b3, c[0][3]);
            c[1][0] = fmaf(a1, b0, c[1][0]); c[1][1] = fmaf(a1, b1, c[1][1]);
            c[1][2] = fmaf(a1, b2, c[1][2]); c[1][3] = fmaf(a1, b3, c[1][3]);
            c[2][0] = fmaf(a2, b0, c[2][0]); c[2][1] = fmaf(a2, b1, c[2][1]);
            c[2][2] = fmaf(a2, b2, c[2][2]); c[2][3] = fmaf(a2, b3, c[2][3]);
            c[3][0] = fmaf(a3, b0, c[3][0]); c[3][1] = fmaf(a3, b1, c[3][1]);
            c[3][2] = fmaf(a3, b2, c[3][2]); c[3][3] = fmaf(a3, b3, c[3][3]);
        }
    }
    float as0 = 0.f, as1 = 0.f, as2 = 0.f, as3 = 0.f;
    float ad0 = 0.f, ad1 = 0.f, ad2 = 0.f, ad3 = 0.f;
    if (act) {
        as0 = att_src2[4 * ty + 0]; as1 = att_src2[4 * ty + 1];
        as2 = att_src2[4 * ty + 2]; as3 = att_src2[4 * ty + 3];
        ad0 = att_dst2[4 * ty + 0]; ad1 = att_dst2[4 * ty + 1];
        ad2 = att_dst2[4 * ty + 2]; ad3 = att_dst2[4 * ty + 3];
    }
    __syncthreads();                              // reuse sX as partials [row][11]
    float* sPs = sX;
    float* sPd = sX + 64 * 11;
#pragma unroll
    for (int i = 0; i < 4; i++) {
        int row = 4 * tx + i;
        int r = r0 + row;
        if (act) {
            if (r < N) {
                float4 hv = make_float4(c[i][0], c[i][1], c[i][2], c[i][3]);
                *((float4*)(h2 + (size_t)r * 40 + 4 * ty)) = hv;
            }
            sPs[row * 11 + ty] = fmaf(c[i][0], as0, fmaf(c[i][1], as1, fmaf(c[i][2], as2, c[i][3] * as3)));
            sPd[row * 11 + ty] = fmaf(c[i][0], ad0, fmaf(c[i][1], ad1, fmaf(c[i][2], ad2, c[i][3] * ad3)));
        }
    }
    __syncthreads();
    if (t < 64) {
        int r = r0 + t;
        if (r < N) {
            float ps = 0.f, pd = 0.f;
#pragma unroll
            for (int j = 0; j < 10; j++) {
                ps += sPs[t * 11 + j];
                pd += sPd[t * 11 + j];
            }
            a_src2[r] = ps;
            a_dst2[r] = pd;
        }
    }
}

// ---------------- layer 2: per-dst-node softmax + aggregate ----------------
// Triple-row gathers: each lane loads a float2 (2 cols of a 40-col h2 row); 20 lanes/row ->
// one instruction covers THREE rows (lanes 60-63 idle). Gather instruction count -> m/3.
__global__ __launch_bounds__(256) void k_node_agg2(
    const int* __restrict__ deg, const int* __restrict__ ssrc,
    const float* __restrict__ a_src2, const float* __restrict__ a_dst2,
    const float* __restrict__ h2, const float* __restrict__ bias2,
    float* __restrict__ out, int N) {
    int d = (blockIdx.x * 256 + threadIdx.x) >> 6;
    int lane = threadIdx.x & 63;
    if (d >= N) return;
    int start = d << 6;
    int m = min(deg[d], SLOT);                    // wave-uniform
    float adst = a_dst2[d];
    // coalesced slot-row load; per-lane logit (0 for lane>=m)
    int s_l = 0; float ex_l = 0.0f;
    if (lane < m) {
        s_l = ssrc[start + lane];
        ex_l = __expf(lrelu(a_src2[s_l] + adst));
    }
    int grp = lane / 20;                          // 0,1,2 gather groups; 3 = idle lanes
    int q20 = lane - grp * 20;                    // col-pair index within row
    bool gact = grp < 3;
    int nin = (m + 2) / 3;                        // gather instructions
    int nblk = (nin + 3) >> 2;                    // blocks of 4 instructions (<=6)
    float aLo = 0.0f, aHi = 0.0f;
    auto loadb = [&](int b, float2* g, float* f) {
#pragma unroll
        for (int k2 = 0; k2 < 4; k2++) {
            int j = 3 * (4 * b + k2) + grp;       // edge index
            int jm = j & 63;                      // clamp for shuffle validity
            int sR = __shfl(s_l, jm);
            float fv = __shfl(ex_l, jm);
            f[k2] = (gact && j < m) ? fv : 0.0f;
            g[k2] = *((const float2*)(h2 + (size_t)sR * 40 + 2 * q20));
        }
    };
    float2 gA[4]; float fA[4];
    if (nblk > 0) loadb(0, gA, fA);
#pragma unroll
    for (int b = 0; b < 6; b++) {
        if (b >= nblk) break;                     // wave-uniform
        float2 gB[4]; float fB[4];
        if (b + 1 < nblk) loadb(b + 1, gB, fB);
#pragma unroll
        for (int k2 = 0; k2 < 4; k2++) {
            aLo = fmaf(fA[k2], gA[k2].x, aLo);
            aHi = fmaf(fA[k2], gA[k2].y, aHi);
        }
        if (b + 1 < nblk) {
#pragma unroll
            for (int k2 = 0; k2 < 4; k2++) { gA[k2] = gB[k2]; fA[k2] = fB[k2]; }
        }
    }
    // merge the 3 edge groups (lanes l, l+20, l+40 hold the same col pair)
    int i1 = (lane + 20) & 63, i2 = (lane + 40) & 63;
    float ml1 = __shfl(aLo, i1), ml2 = __shfl(aLo, i2);
    float mh1 = __shfl(aHi, i1), mh2 = __shfl(aHi, i2);
    aLo += ml1 + ml2;
    aHi += mh1 + mh2;
    // denominator: full-wave reduce of per-lane logits
    float t = ex_l;
#pragma unroll
    for (int off = 32; off; off >>= 1) t += __shfl_xor(t, off);
    if (lane < 20) {
        float2 bz = ((const float2*)bias2)[lane];
        float oLo = aLo / (t + EPS) + bz.x;
        float oHi = aHi / (t + EPS) + bz.y;
        *((float2*)(out + (size_t)d * 40 + 2 * lane)) = make_float2(oLo, oHi);
    }
}

// ---------------- launch ----------------
extern "C" void kernel_launch(void* const* d_in, const int* in_sizes, int n_in,
                              void* d_out, int out_size, void* d_ws, size_t ws_size,
                              hipStream_t stream) {
    const float* x        = (const float*)d_in[0];
    const int*   ei       = (const int*)d_in[1];
    const float* W1       = (const float*)d_in[2];
    const float* att_src1 = (const float*)d_in[3];
    const float* att_dst1 = (const float*)d_in[4];
    const float* bias1    = (const float*)d_in[5];
    const float* W2       = (const float*)d_in[6];
    const float* att_src2 = (const float*)d_in[7];
    const float* att_dst2 = (const float*)d_in[8];
    const float* bias2    = (const float*)d_in[9];
    float* out = (float*)d_out;

    const int N = in_sizes[0] / 128;   // 50000
    const int E = in_sizes[1] / 2;     // 800000
    const int* src = ei;
    const int* dst = ei + E;

    // workspace layout (slot-CSR: no rowptr/cursor/blocksum; ssrc is N*64 slots)
    float* ws = (float*)d_ws;
    size_t off = 0;
    int*   deg      = (int*)(ws + off); off += (size_t)N;
    int*   ssrc     = (int*)(ws + off); off += (size_t)N * SLOT;
    unsigned short* h1b = (unsigned short*)(ws + off); off += (size_t)N * 32;  // bf16 N*64
    float* a_src1   = ws + off; off += (size_t)N * 8;
    float* a_dst1   = ws + off; off += (size_t)N * 8;
    float* xx       = ws + off; off += (size_t)N * 64;
    float* h2       = ws + off; off += (size_t)N * 40;
    float* a_src2   = ws + off; off += (size_t)N;
    float* a_dst2   = ws + off; off += (size_t)N;

    const int B = 256;
    int G1 = (N + 63) / 64;               // gemm blocks (782)
    int D  = (E / 8 + 255) / 256;         // scatter blocks (8 edges/thread, 391)

    hipMemsetAsync(deg, 0, (size_t)N * sizeof(int), stream);
    // single-pass slot-CSR scatter fused with gemm1 (+ attention dots): scatter blocks
    // first (critical path), GEMM co-schedules behind atomic latency
    k_gemm1_scat<<<D + G1, B, 0, stream>>>(x, W1, att_src1, att_dst1, h1b, a_src1, a_dst1,
                                           N, D, src, dst, deg, ssrc, E);
    k_node_agg1<<<(N + 3) / 4, B, 0, stream>>>(deg, ssrc, a_src1, a_dst1, h1b, bias1, xx, N);
    k_gemm2<<<G1, B, 0, stream>>>(xx, W2, att_src2, att_dst2, h2, a_src2, a_dst2, N);
    k_node_agg2<<<(N + 3) / 4, B, 0, stream>>>(deg, ssrc, a_src2, a_dst2, h2, bias2, out, N);
}